// Round 4
// baseline (152.754 us; speedup 1.0000x reference)
//
#include <hip/hip_runtime.h>
#include <cmath>

#define NA 8400
#define NC 80
#define BS 16
#define NMAX 64
#define TOPKK 13
#define CAP 768
#define NN_REG 12             // CAP / 64
#define CEPS 1e-9f
#define PIF 3.14159265358979323846f

// d_out layout (float32, concatenated)
#define OFF_LABELS  0
#define OFF_CIRCLES 134400
#define OFF_SCORES  537600
#define OFF_FG      11289600
#define OFF_TGI     11424000

// workspace layout (bytes)
//   colbits : [0, 1075200)           134400 x u64  (bit j set => mask_pos[b,j,a]=1)
//   ovkey   : [1075200, 2150400)     134400 x u64  (f32bits(iou)<<32 | (63-j))
//   posal   : [2150400, 2154496)     1024 x u32
//   posov   : [2154496, 2158592)     1024 x u32
//   tgiE    : [2158592, 2696192)     134400 x i32
//   alignv  : [2696192, 3233792)     134400 x f32
#define WS_OVKEY   1075200
#define WS_POSAL   2150400
#define WS_POSOV   2154496
#define WS_TGI     2158592
#define WS_ALIGN   2696192
#define ZERO_WS_F4 134912     // (colbits+ovkey+posal+posov)/16

__device__ __forceinline__ float circle_iou_dev(float gx, float gy, float r1,
                                                float px, float py, float r2) {
    float dx = gx - px, dy = gy - py;
    float d = sqrtf(dx * dx + dy * dy + CEPS);
    float a1 = PIF * r1 * r1, a2 = PIF * r2 * r2;
    float d2 = d * d;
    float c1 = (d2 + r1 * r1 - r2 * r2) / (2.0f * d * r1 + CEPS);
    float c2 = (d2 + r2 * r2 - r1 * r1) / (2.0f * d * r2 + CEPS);
    c1 = fminf(fmaxf(c1, -1.0f), 1.0f);
    c2 = fminf(fmaxf(c2, -1.0f), 1.0f);
    float tri = fmaxf((r1 + r2 - d) * (d + r1 - r2) * (d - r1 + r2) * (d + r1 + r2), 0.0f);
    float lens = r1 * r1 * acosf(c1) + r2 * r2 * acosf(c2) - 0.5f * sqrtf(tri);
    float inter;
    if (d >= r1 + r2)             inter = 0.0f;
    else if (d <= fabsf(r1 - r2)) { float rm = fminf(r1, r2); inter = PIF * rm * rm; }
    else                          inter = lens;
    return inter / (a1 + a2 - inter + CEPS);
}

// K0: zero colbits + ovkey + posal + posov (2.16 MB).
__global__ __launch_bounds__(256) void k0_zero(float4* __restrict__ wsz)
{
    int i = blockIdx.x * 256 + threadIdx.x;
    if (i < ZERO_WS_F4) wsz[i] = make_float4(0.f, 0.f, 0.f, 0.f);
}

// K1: one block per (b, j). Analytic bbox enumeration with wave-aggregated
// compaction; dense align compute + ovkey publish; then wave-0-only,
// barrier-free, register-resident 13-pass argmax (value desc, anchor-idx asc),
// mask-based zero-filler, and fire-and-forget colbits atomics.
__global__ __launch_bounds__(256) void k1_topk(
    const float* __restrict__ pd_scores, const float* __restrict__ pd_circles,
    const int* __restrict__ gt_labels, const float* __restrict__ gt_bboxes,
    const float* __restrict__ mask_gt, unsigned long long* __restrict__ colbits,
    unsigned long long* __restrict__ ovkey)
{
    __shared__ int   s_cidx[CAP];
    __shared__ float s_cval[CAP];
    __shared__ float s_low[64];            // align of anchors 0..63 (0 default)
    __shared__ int   s_ncand;

    const int row = blockIdx.x;            // b*64 + j
    const int b = row >> 6, j = row & 63;
    const int t = threadIdx.x;
    const int lane = t & 63, wv = t >> 6;

    if (mask_gt[row] <= 0.0f) return;      // ws pre-zeroed by K0

    const float gx = gt_bboxes[row * 3 + 0];
    const float gy = gt_bboxes[row * 3 + 1];
    const float gr = gt_bboxes[row * 3 + 2];
    int lab = gt_labels[row];
    lab = min(max(lab, 0), NC - 1);

    if (t == 0) s_ncand = 0;
    if (t < 64) s_low[t] = 0.0f;
    __syncthreads();

    // in-gt bits for anchors 0..63 (level-0 row 0: x=(i+0.5)*8, y=4) — kept
    // in a wave-0 register (used only by wave 0 in phase D).
    unsigned long long m_ingt0 = 0ull;
    if (wv == 0) {
        float ax = ((float)lane + 0.5f) * 8.0f, ay = 4.0f;
        float dx = gx - ax, dy = gy - ay;
        m_ingt0 = __ballot(sqrtf(dx * dx + dy * dy) <= gr);
    }

    // phase A: analytic bbox enumeration + exact membership test, with
    // wave-aggregated slot allocation (one LDS atomic per wave per iter).
    const int strides_[3] = {8, 16, 32};
    const int ns_[3]      = {80, 40, 20};
    const int bases_[3]   = {0, 6400, 8000};
#pragma unroll
    for (int l = 0; l < 3; ++l) {
        const float sl = (float)strides_[l];
        const int n_l = ns_[l], base_l = bases_[l];
        const float inv = 1.0f / sl;
        int y0 = (int)ceilf((gy - gr) * inv - 0.5f) - 1;
        int y1 = (int)floorf((gy + gr) * inv - 0.5f) + 1;
        int x0 = (int)ceilf((gx - gr) * inv - 0.5f) - 1;
        int x1 = (int)floorf((gx + gr) * inv - 0.5f) + 1;
        y0 = max(y0, 0); x0 = max(x0, 0);
        y1 = min(y1, n_l - 1); x1 = min(x1, n_l - 1);
        const int W = x1 - x0 + 1, H = y1 - y0 + 1;
        if (W > 0 && H > 0) {
            const int cells = W * H;
            const int kk = (cells + 255) >> 8;      // uniform trip count
            for (int k = 0; k < kk; ++k) {
                const int c = k * 256 + t;
                bool found = false; int aidx = 0;
                if (c < cells) {
                    const int q = c / W;
                    const int iy = y0 + q, ix = x0 + (c - q * W);
                    float ax = ((float)ix + 0.5f) * sl;
                    float ay = ((float)iy + 0.5f) * sl;
                    float dx = gx - ax, dy = gy - ay;
                    found = (sqrtf(dx * dx + dy * dy) <= gr);
                    aidx = base_l + iy * n_l + ix;
                }
                unsigned long long m = __ballot(found);
                if (m) {
                    const int cnt = __popcll(m);
                    const int ldr = __ffsll(m) - 1;
                    int base = 0;
                    if (lane == ldr) base = atomicAdd(&s_ncand, cnt);
                    base = __shfl(base, ldr);
                    if (found) {
                        int p = base + __popcll(m & ((1ull << lane) - 1ull));
                        if (p < CAP) s_cidx[p] = aidx;
                    }
                }
            }
        }
    }
    __syncthreads();
    const int n = min(s_ncand, CAP);

    // phase B: dense align compute over candidates + overlap-argmax publish.
    for (int c = t; c < n; c += 256) {
        int a = s_cidx[c];
        size_t pi = (size_t)(b * NA + a);
        float px = pd_circles[pi * 3 + 0];
        float py = pd_circles[pi * 3 + 1];
        float pr = pd_circles[pi * 3 + 2];
        float iou = circle_iou_dev(gx, gy, gr, px, py, pr);
        float sc  = pd_scores[pi * NC + lab];
        float o2 = iou * iou;
        float v = sc * (o2 * o2 * o2);
        s_cval[c] = v;
        if (a < 64) s_low[a] = v;
        unsigned long long key =
            ((unsigned long long)__float_as_uint(iou) << 32) |
            (unsigned long long)(63 - j);
        atomicMax(&ovkey[(size_t)b * NA + a], key);
    }
    __syncthreads();

    if (wv != 0) return;                   // waves 1..3: no further barriers

    // phase C: register-resident 13-pass argmax on wave 0 (barrier-free).
    float rv[NN_REG]; int ri[NN_REG];
#pragma unroll
    for (int s = 0; s < NN_REG; ++s) {
        int c = s * 64 + lane;
        bool ok = (c < n);
        rv[s] = ok ? s_cval[c] : -1.0f;
        ri[s] = ok ? s_cidx[c] : (1 << 30);
    }

    int selv[TOPKK];
#pragma unroll
    for (int s = 0; s < TOPKK; ++s) selv[s] = 0;
    int nsel = 0;

    for (int it = 0; it < TOPKK; ++it) {
        float bv = -1.0f; int bi = 1 << 30;
#pragma unroll
        for (int s = 0; s < NN_REG; ++s)
            if (rv[s] > bv || (rv[s] == bv && ri[s] < bi)) { bv = rv[s]; bi = ri[s]; }
        for (int off = 32; off > 0; off >>= 1) {
            float ov = __shfl_xor(bv, off);
            int   oi = __shfl_xor(bi, off);
            if (ov > bv || (ov == bv && oi < bi)) { bv = ov; bi = oi; }
        }
        if (bv <= 0.0f) break;             // wave-uniform
#pragma unroll
        for (int s = 0; s < TOPKK; ++s) if (s == nsel) selv[s] = bi;
        nsel++;
#pragma unroll
        for (int s = 0; s < NN_REG; ++s) if (ri[s] == bi) rv[s] = -1.0f;
    }

    // phase D: zero-filler via masks, replicated wave-uniformly.
    // Reference top_k fills remaining slots with the globally lowest-index
    // zero-valued entries (always within anchors 0..63); keep in-gt ones.
    {
        float lowv = s_low[lane];
        unsigned long long mpos = __ballot(lowv > 0.0f);
        unsigned long long zeros = ~mpos;  // always >= 46 bits set
        int r = TOPKK - nsel;
        while (r > 0 && zeros) {
            int idx = __ffsll(zeros) - 1;
            zeros &= zeros - 1ull;
            r--;
            if ((m_ingt0 >> idx) & 1ull) {
#pragma unroll
                for (int s = 0; s < TOPKK; ++s) if (s == nsel) selv[s] = idx;
                nsel++;
            }
        }
    }

    // phase E: set bit j in each selected anchor's GT column (lane 0).
    if (lane == 0) {
#pragma unroll
        for (int s = 0; s < TOPKK; ++s)
            if (s < nsel)
                atomicOr(&colbits[(size_t)b * NA + selv[s]], 1ull << j);
    }
}

// K2: one thread per (b, a). Contested anchors resolved by the precomputed
// overlap-argmax key (single 8B load); outputs + posal/posov atomicMax.
__global__ __launch_bounds__(256) void k2_resolve(
    const float* __restrict__ pd_scores, const float* __restrict__ pd_circles,
    const float* __restrict__ anc, const int* __restrict__ gt_labels,
    const float* __restrict__ gt_bboxes, const float* __restrict__ mask_gt,
    const unsigned long long* __restrict__ colbits,
    const unsigned long long* __restrict__ ovkey,
    float* __restrict__ out, int* __restrict__ tgiE, float* __restrict__ alignv,
    unsigned int* __restrict__ posal, unsigned int* __restrict__ posov)
{
    const int idx = blockIdx.x * 256 + threadIdx.x;   // < 134400
    const int b = idx / NA;
    const int a = idx - b * NA;

    const unsigned long long col = colbits[idx];
    const int cnt = __popcll(col);

    int tgi = 0, fg = 0;
    if (cnt == 1) { fg = 1; tgi = __ffsll((unsigned long long)col) - 1; }
    else if (cnt > 1) {
        fg = 1;
        const unsigned long long key = ovkey[idx];
        const unsigned int ib = (unsigned int)(key >> 32);
        // best iou == 0 -> reference row is all zeros -> argmax = 0
        tgi = (ib != 0u) ? (63 - (int)(key & 63ull)) : 0;
    }

    const int gl = gt_labels[b * NMAX + tgi];
    const float gx = gt_bboxes[(b * NMAX + tgi) * 3 + 0];
    const float gy = gt_bboxes[(b * NMAX + tgi) * 3 + 1];
    const float gr = gt_bboxes[(b * NMAX + tgi) * 3 + 2];

    out[OFF_LABELS + idx] = (float)max(gl, 0);
    out[OFF_CIRCLES + (size_t)idx * 3 + 0] = gx;
    out[OFF_CIRCLES + (size_t)idx * 3 + 1] = gy;
    out[OFF_CIRCLES + (size_t)idx * 3 + 2] = gr;
    out[OFF_FG + idx]  = (float)fg;
    out[OFF_TGI + idx] = (float)tgi;
    tgiE[idx] = fg ? tgi : -1;

    float alg = 0.0f;
    if (fg) {
        float ovv = 0.0f;
        float mgv = mask_gt[b * NMAX + tgi];
        float ax = anc[2 * a], ay = anc[2 * a + 1];
        float dx = gx - ax, dy = gy - ay;
        if (mgv > 0.0f && sqrtf(dx * dx + dy * dy) <= gr) {
            float px = pd_circles[(size_t)idx * 3 + 0];
            float py = pd_circles[(size_t)idx * 3 + 1];
            float pr = pd_circles[(size_t)idx * 3 + 2];
            float iou = circle_iou_dev(gx, gy, gr, px, py, pr);
            int lab = min(max(gl, 0), NC - 1);
            float sc = pd_scores[((size_t)b * NA + a) * NC + lab];
            ovv = iou;
            float o2 = iou * iou;
            alg = sc * (o2 * o2 * o2);
        }
        atomicMax(&posal[b * NMAX + tgi], __float_as_uint(alg));
        atomicMax(&posov[b * NMAX + tgi], __float_as_uint(ovv));
    }
    alignv[idx] = alg;
}

// K4: dense write of target_scores — each float4 covers 4 classes of one
// anchor row; bg rows are zero, fg rows have norm at the label slot.
__global__ __launch_bounds__(256) void k4_dense(
    const int* __restrict__ tgiE, const float* __restrict__ alignv,
    const unsigned int* __restrict__ posal, const unsigned int* __restrict__ posov,
    const int* __restrict__ gt_labels, float4* __restrict__ scores4)
{
    const int f = blockIdx.x * 256 + threadIdx.x;     // < 2,688,000
    const int a_idx = f / 20;                         // anchor global idx
    const int p = f - a_idx * 20;                     // float4 slot in row

    float4 v = make_float4(0.f, 0.f, 0.f, 0.f);
    const int tg = tgiE[a_idx];
    if (tg >= 0) {
        const int b = a_idx / NA;
        const float pa = __uint_as_float(posal[b * NMAX + tg]);
        const float po = __uint_as_float(posov[b * NMAX + tg]);
        const float norm = alignv[a_idx] * po / (pa + CEPS);
        const int lab = max(gt_labels[b * NMAX + tg], 0);
        if ((lab >> 2) == p) ((float*)&v)[lab & 3] = norm;
    }
    scores4[f] = v;
}

extern "C" void kernel_launch(void* const* d_in, const int* in_sizes, int n_in,
                              void* d_out, int out_size, void* d_ws, size_t ws_size,
                              hipStream_t stream) {
    const float* pd_scores  = (const float*)d_in[0];
    const float* pd_circles = (const float*)d_in[1];
    const float* anc        = (const float*)d_in[2];
    const int*   gt_labels  = (const int*)d_in[3];
    const float* gt_bboxes  = (const float*)d_in[4];
    const float* mask_gt    = (const float*)d_in[5];
    float* out = (float*)d_out;

    char* ws = (char*)d_ws;
    unsigned long long* colbits = (unsigned long long*)ws;
    unsigned long long* ovkey   = (unsigned long long*)(ws + WS_OVKEY);
    unsigned int* posal = (unsigned int*)(ws + WS_POSAL);
    unsigned int* posov = (unsigned int*)(ws + WS_POSOV);
    int*   tgiE   = (int*)(ws + WS_TGI);
    float* alignv = (float*)(ws + WS_ALIGN);

    k0_zero<<<(ZERO_WS_F4 + 255) / 256, 256, 0, stream>>>((float4*)ws);
    k1_topk<<<BS * NMAX, 256, 0, stream>>>(pd_scores, pd_circles, gt_labels,
                                           gt_bboxes, mask_gt, colbits, ovkey);
    k2_resolve<<<(BS * NA) / 256, 256, 0, stream>>>(pd_scores, pd_circles, anc,
                                                    gt_labels, gt_bboxes, mask_gt,
                                                    colbits, ovkey, out, tgiE,
                                                    alignv, posal, posov);
    k4_dense<<<(BS * NA * NC / 4) / 256, 256, 0, stream>>>(tgiE, alignv, posal,
                                                           posov, gt_labels,
                                                           (float4*)(out + OFF_SCORES));
}